// Round 6
// baseline (145.864 us; speedup 1.0000x reference)
//
#include <hip/hip_runtime.h>

#define H_LEN 16384
#define ATT_DIM 512
#define DUNITS 1024
#define EPROJS 512
#define NCH 10
#define KFILT 201
#define PAD 100
#define N_PREV 128
#define HB 32          // h per k_score block
#define NB_SCORE 512   // k_score blocks
#define NB_FIN 256     // k_final blocks
#define NCOVP 16       // cov partials (n-groups of 8)

// ---------------------------------------------------------------------------
// K1: fused prep. 385 blocks x 256.  (verified round-5 form)
//  b in [0,256)   : float4 copy + partial coverage (att_prev read ONCE).
//  b in [256,384) : dz[a] = mlp_dec_w[a,:] . dec_z (one wave per a)
//  b == 384       : zero out_c + transpose watt[512][10] -> wattT[10][512]
__global__ __launch_bounds__(256) void k_prep(const float* __restrict__ att_prev,
                                              const float* __restrict__ mlp_dec_w,
                                              const float* __restrict__ dec_z,
                                              const float* __restrict__ watt,
                                              float* __restrict__ out_prev,
                                              float* __restrict__ cov16,
                                              float* __restrict__ dz,
                                              float* __restrict__ wattT,
                                              float* __restrict__ out_c) {
    int b = blockIdx.x, tid = threadIdx.x;
    if (b < 256) {
        const float4* ap4 = (const float4*)att_prev;
        float4* op4 = (float4*)out_prev;
        float4* cv4 = (float4*)cov16;
        int hb = b >> 4, q = b & 15;
        int idx0 = hb * 256 + tid;               // float4 index in a row: [0, 4096)
        float4 s = {0.f, 0.f, 0.f, 0.f};
        #pragma unroll
        for (int n = q * 8; n < q * 8 + 8; ++n) {
            float4 v = ap4[n * (H_LEN / 4) + idx0];
            s.x += v.x; s.y += v.y; s.z += v.z; s.w += v.w;
            op4[n * (H_LEN / 4) + idx0] = v;
        }
        cv4[q * (H_LEN / 4) + idx0] = s;
    } else if (b < 384) {
        int lane = tid & 63;
        int a = (b - 256) * 4 + (tid >> 6);
        const float* row = mlp_dec_w + a * DUNITS;
        float s = 0.f;
        #pragma unroll
        for (int t = 0; t < DUNITS / 64; ++t) s += row[lane + 64 * t] * dec_z[lane + 64 * t];
        #pragma unroll
        for (int off = 32; off > 0; off >>= 1) s += __shfl_xor(s, off, 64);
        if (lane == 0) dz[a] = s;
    } else {
        out_c[tid] = 0.f;
        out_c[tid + 256] = 0.f;
        int a = tid * 2;                          // transpose 20 KB, once
        #pragma unroll
        for (int c = 0; c < NCH; ++c) {
            wattT[c * ATT_DIM + a]     = watt[a * NCH + c];
            wattT[c * ATT_DIM + a + 1] = watt[(a + 1) * NCH + c];
        }
    }
}

// ---------------------------------------------------------------------------
// K2: conv + score + per-block softmax partials + unnormalized context partial.
// 512 blocks x 512 threads (8 waves) -> 16 waves/CU resident (2 blocks/CU),
// double the latency hiding of the 256-thread version. Wave wv owns
// a in [64*wv, 64*wv+64), lane owns ONE a: W[10] per thread, all loads
// lane-consecutive coalesced, ~100 live VGPR (no spills at the 128 cap).
__global__ __launch_bounds__(512, 4) void k_score(const float* __restrict__ cov16,
                                                  const float* __restrict__ cw,
                                                  const float* __restrict__ pre,
                                                  const float* __restrict__ mask,
                                                  const float* __restrict__ dz,
                                                  const float* __restrict__ wattT,
                                                  const float* __restrict__ gv,
                                                  const float* __restrict__ gb,
                                                  const float* __restrict__ enc,
                                                  float* __restrict__ vbuf,
                                                  float* __restrict__ pm,
                                                  float* __restrict__ ps,
                                                  float* __restrict__ pcb) {
    __shared__ float cov_s[HB + 2 * PAD];   // 232
    __shared__ float mask_s[HB];
    __shared__ float pc[16][NCH][HB];       // partial conv per tap-16th (20 KB)
    __shared__ float cfT[HB * 12];          // conv result, [h][c] padded to 12
    __shared__ float ew[8][HB];             // per-wave e partials
    __shared__ float wt[HB];                // exp(v - M_b)

    int tid = threadIdx.x, b = blockIdx.x;
    int h0 = b * HB;
    int lane = tid & 63, wv = tid >> 6;     // wv in [0,8)

    // stage LDS: cov window (sum the 16 n-partials) + mask
    for (int i = tid; i < HB + 2 * PAD; i += 512) {
        int g = h0 - PAD + i;
        float s = 0.f;
        if (g >= 0 && g < H_LEN) {
            #pragma unroll
            for (int q = 0; q < NCOVP; ++q) s += cov16[q * H_LEN + g];
        }
        cov_s[i] = s;
    }
    if (tid < HB) mask_s[tid] = mask[h0 + tid];

    // per-thread weights, ALL coalesced (a = 64*wv + lane)
    int a = (wv << 6) + lane;
    float dz1 = dz[a];
    float gv1 = gv[a];
    float W[NCH];
    #pragma unroll
    for (int c = 0; c < NCH; ++c) W[c] = wattT[c * ATT_DIM + a];
    float bias = gb[0];
    __syncthreads();

    // conv: 16 tap-groups (q = tid>>5, ~13 taps each), h = tid&31
    {
        int h = tid & 31, q = tid >> 5;            // q in [0,16)
        int k0 = (q * KFILT) / 16, k1 = ((q + 1) * KFILT) / 16;
        float acc[NCH];
        #pragma unroll
        for (int c = 0; c < NCH; ++c) acc[c] = 0.f;
        for (int k = k0; k < k1; ++k) {
            float s = cov_s[h + k];
            #pragma unroll
            for (int c = 0; c < NCH; ++c) acc[c] += s * cw[c * KFILT + k];
        }
        #pragma unroll
        for (int c = 0; c < NCH; ++c) pc[q][c][h] = acc[c];   // distinct slot per q
    }
    __syncthreads();
    for (int i = tid; i < NCH * HB; i += 512) {     // 320 entries
        int c = i >> 5, h = i & 31;
        float s = 0.f;
        #pragma unroll
        for (int q = 0; q < 16; ++q) s += pc[q][c][h];
        cfT[h * 12 + c] = s;
    }
    __syncthreads();

    // score: every thread computes its 1-a contribution for ALL 32 h.
    // pre reads: coalesced scalar; cf reads: 3 broadcast ds_read_b128 per h.
    float ea[HB];
    #pragma unroll
    for (int hc = 0; hc < HB; hc += 8) {
        float Pr[8];
        #pragma unroll
        for (int j = 0; j < 8; ++j) Pr[j] = pre[(h0 + hc + j) * ATT_DIM + a];
        #pragma unroll
        for (int j = 0; j < 8; ++j) {
            int h = hc + j;
            const float4* cp = (const float4*)&cfT[h * 12];
            float4 c0 = cp[0], c1 = cp[1], c2 = cp[2];
            float ch[NCH] = {c0.x, c0.y, c0.z, c0.w, c1.x, c1.y, c1.z, c1.w, c2.x, c2.y};
            float x = Pr[j] + dz1;
            #pragma unroll
            for (int c = 0; c < NCH; ++c) x += ch[c] * W[c];
            x = fminf(fmaxf(x, -15.f), 15.f);
            float z = __expf(2.f * x);                      // tanh via exp + rcp
            float t = (z - 1.f) * __builtin_amdgcn_rcpf(z + 1.f);
            ea[h] = t * gv1;
        }
    }

    // reduce-scatter butterfly, single shuffle per fold (31 + 1 shuffles).
    // After 5 halving steps lane holds h = lane>>1; off=1 completes the sum.
    #pragma unroll
    for (int k = 0; k < 16; ++k) {
        float lo = ea[k], hi = ea[k + 16];
        float send = (lane & 32) ? lo : hi;
        float recv = __shfl_xor(send, 32, 64);
        ea[k] = ((lane & 32) ? hi : lo) + recv;
    }
    #pragma unroll
    for (int k = 0; k < 8; ++k) {
        float lo = ea[k], hi = ea[k + 8];
        float send = (lane & 16) ? lo : hi;
        float recv = __shfl_xor(send, 16, 64);
        ea[k] = ((lane & 16) ? hi : lo) + recv;
    }
    #pragma unroll
    for (int k = 0; k < 4; ++k) {
        float lo = ea[k], hi = ea[k + 4];
        float send = (lane & 8) ? lo : hi;
        float recv = __shfl_xor(send, 8, 64);
        ea[k] = ((lane & 8) ? hi : lo) + recv;
    }
    #pragma unroll
    for (int k = 0; k < 2; ++k) {
        float lo = ea[k], hi = ea[k + 2];
        float send = (lane & 4) ? lo : hi;
        float recv = __shfl_xor(send, 4, 64);
        ea[k] = ((lane & 4) ? hi : lo) + recv;
    }
    {
        float lo = ea[0], hi = ea[1];
        float send = (lane & 2) ? lo : hi;
        float recv = __shfl_xor(send, 2, 64);
        ea[0] = ((lane & 2) ? hi : lo) + recv;
    }
    ea[0] += __shfl_xor(ea[0], 1, 64);
    if ((lane & 1) == 0) ew[wv][lane >> 1] = ea[0];
    __syncthreads();

    // wave 0: combine 8 wave-partials, scale, block softmax partials
    if (wv == 0) {
        float v = -1e30f;
        if (lane < HB) {
            float e = 0.f;
            #pragma unroll
            for (int w = 0; w < 8; ++w) e += ew[w][lane];
            v = 2.f * (e + bias + mask_s[lane]);
            vbuf[h0 + lane] = v;
        }
        float m = v;
        #pragma unroll
        for (int off = 32; off > 0; off >>= 1) m = fmaxf(m, __shfl_xor(m, off, 64));
        float ev = (lane < HB) ? __expf(v - m) : 0.f;
        if (lane < HB) wt[lane] = ev;
        float s = ev;
        #pragma unroll
        for (int off = 32; off > 0; off >>= 1) s += __shfl_xor(s, off, 64);
        if (lane == 0) { pm[b] = m; ps[b] = s; }
    }
    __syncthreads();

    // unnormalized context partial: thread t owns enc col t (coalesced scalar)
    float ca0 = 0.f, ca1 = 0.f;
    #pragma unroll
    for (int h = 0; h < HB; h += 2) {
        ca0 += wt[h]     * enc[(h0 + h) * EPROJS + tid];
        ca1 += wt[h + 1] * enc[(h0 + h + 1) * EPROJS + tid];
    }
    pcb[b * EPROJS + tid] = ca0 + ca1;
}

// ---------------------------------------------------------------------------
// K3: finalize. 256 blocks x 256 thr. Redundant merge of 512 (m,s) partials
// (2 KB, L2-hot); block b writes w for 64 h; reduces pcb rows {2b,2b+1} into
// out_c with rescale, via atomics (256 adds/address).  (verified form)
__global__ __launch_bounds__(256) void k_final(const float* __restrict__ vbuf,
                                               const float* __restrict__ pm,
                                               const float* __restrict__ ps,
                                               const float* __restrict__ pcb,
                                               float* __restrict__ out_w,
                                               float* __restrict__ out_c) {
    __shared__ float redA[4], redB[4];
    int tid = threadIdx.x, b = blockIdx.x;
    int lane = tid & 63, wv = tid >> 6;

    float m0 = pm[tid], m1 = pm[tid + 256];
    float s0 = ps[tid], s1 = ps[tid + 256];
    float m = fmaxf(m0, m1);
    #pragma unroll
    for (int off = 32; off > 0; off >>= 1) m = fmaxf(m, __shfl_xor(m, off, 64));
    if (lane == 0) redA[wv] = m;
    __syncthreads();
    float M = fmaxf(fmaxf(redA[0], redA[1]), fmaxf(redA[2], redA[3]));
    float s = s0 * __expf(m0 - M) + s1 * __expf(m1 - M);
    #pragma unroll
    for (int off = 32; off > 0; off >>= 1) s += __shfl_xor(s, off, 64);
    if (lane == 0) redB[wv] = s;
    __syncthreads();
    float S = redB[0] + redB[1] + redB[2] + redB[3];
    float rinv = 1.f / S;

    // w output: 64 h per block
    if (tid < 64) {
        int h = b * 64 + tid;
        out_w[h] = __expf(vbuf[h] - M) * rinv;
    }

    // context reduction: rows 2b, 2b+1 of pcb
    int r0 = 2 * b, r1 = 2 * b + 1;
    float sc0 = __expf(pm[r0] - M) * rinv;
    float sc1 = __expf(pm[r1] - M) * rinv;
    float v0 = pcb[r0 * EPROJS + tid] * sc0 + pcb[r1 * EPROJS + tid] * sc1;
    float v1 = pcb[r0 * EPROJS + tid + 256] * sc0 + pcb[r1 * EPROJS + tid + 256] * sc1;
    atomicAdd(&out_c[tid], v0);
    atomicAdd(&out_c[tid + 256], v1);
}

// ---------------------------------------------------------------------------
extern "C" void kernel_launch(void* const* d_in, const int* in_sizes, int n_in,
                              void* d_out, int out_size, void* d_ws, size_t ws_size,
                              hipStream_t stream) {
    const float* dec_z      = (const float*)d_in[0];
    const float* att_prev   = (const float*)d_in[1];
    const float* pre        = (const float*)d_in[2];
    const float* enc_h      = (const float*)d_in[3];
    const float* mask       = (const float*)d_in[4];
    const float* loc_conv_w = (const float*)d_in[5];
    const float* mlp_att_w  = (const float*)d_in[6];
    const float* mlp_dec_w  = (const float*)d_in[7];
    const float* gvec_w     = (const float*)d_in[8];
    const float* gvec_b     = (const float*)d_in[9];

    float* out_c    = (float*)d_out;                  // [512]
    float* out_prev = out_c + EPROJS;                 // [128*16384]
    float* out_w    = out_prev + N_PREV * H_LEN;      // [16384]

    float* ws    = (float*)d_ws;
    float* cov16 = ws;                                // 16*16384
    float* dz    = cov16 + NCOVP * H_LEN;             // 512
    float* vb    = dz + ATT_DIM;                      // 16384
    float* pm    = vb + H_LEN;                        // 512
    float* ps    = pm + NB_SCORE;                     // 512
    float* pcb   = ps + NB_SCORE;                     // 512*512
    float* wattT = pcb + NB_SCORE * EPROJS;           // 10*512

    k_prep<<<385, 256, 0, stream>>>(att_prev, mlp_dec_w, dec_z, mlp_att_w,
                                    out_prev, cov16, dz, wattT, out_c);
    k_score<<<NB_SCORE, 512, 0, stream>>>(cov16, loc_conv_w, pre, mask, dz, wattT,
                                          gvec_w, gvec_b, enc_h, vb, pm, ps, pcb);
    k_final<<<NB_FIN, 256, 0, stream>>>(vb, pm, ps, pcb, out_w, out_c);
}

// Round 7
// 139.278 us; speedup vs baseline: 1.0473x; 1.0473x over previous
//
#include <hip/hip_runtime.h>

#define H_LEN 16384
#define ATT_DIM 512
#define DUNITS 1024
#define EPROJS 512
#define NCH 10
#define KFILT 201
#define PAD 100
#define N_PREV 128
#define HB 32          // h per k_score block
#define NB_SCORE 512   // k_score blocks
#define NB_FIN 256     // k_final blocks
#define NCOVP 16       // cov partials (n-groups of 8)

// ---------------------------------------------------------------------------
// K1: prep (no copy — copy moved to k_score tail, where att_prev is L3-hot).
//  b in [0,256)   : partial coverage. h-chunk = b>>4, n-group = b&15 (8 n).
//  b in [256,384) : dz[a] = mlp_dec_w[a,:] . dec_z (one wave per a)
//  b == 384       : zero out_c + transpose watt[512][10] -> wattT[10][512]
__global__ __launch_bounds__(256) void k_prep(const float* __restrict__ att_prev,
                                              const float* __restrict__ mlp_dec_w,
                                              const float* __restrict__ dec_z,
                                              const float* __restrict__ watt,
                                              float* __restrict__ cov16,
                                              float* __restrict__ dz,
                                              float* __restrict__ wattT,
                                              float* __restrict__ out_c) {
    int b = blockIdx.x, tid = threadIdx.x;
    if (b < 256) {
        const float4* ap4 = (const float4*)att_prev;
        float4* cv4 = (float4*)cov16;
        int hb = b >> 4, q = b & 15;
        int idx0 = hb * 256 + tid;               // float4 index in a row: [0, 4096)
        float4 s = {0.f, 0.f, 0.f, 0.f};
        #pragma unroll
        for (int n = q * 8; n < q * 8 + 8; ++n) {
            float4 v = ap4[n * (H_LEN / 4) + idx0];
            s.x += v.x; s.y += v.y; s.z += v.z; s.w += v.w;
        }
        cv4[q * (H_LEN / 4) + idx0] = s;
    } else if (b < 384) {
        int lane = tid & 63;
        int a = (b - 256) * 4 + (tid >> 6);
        const float* row = mlp_dec_w + a * DUNITS;
        float s = 0.f;
        #pragma unroll
        for (int t = 0; t < DUNITS / 64; ++t) s += row[lane + 64 * t] * dec_z[lane + 64 * t];
        #pragma unroll
        for (int off = 32; off > 0; off >>= 1) s += __shfl_xor(s, off, 64);
        if (lane == 0) dz[a] = s;
    } else {
        out_c[tid] = 0.f;
        out_c[tid + 256] = 0.f;
        int a = tid * 2;                          // transpose 20 KB, once
        #pragma unroll
        for (int c = 0; c < NCH; ++c) {
            wattT[c * ATT_DIM + a]     = watt[a * NCH + c];
            wattT[c * ATT_DIM + a + 1] = watt[(a + 1) * NCH + c];
        }
    }
}

// ---------------------------------------------------------------------------
// K2: conv + score + per-block softmax partials + unnormalized context partial
// + att_prev copy slice (tail; L3-hot, no barrier). 512 blocks x 256 thr,
// wave wv owns a in [128wv,128wv+128), lane owns 2 consecutive a:
// W[2][10] per thread (no spills), all global loads coalesced float2.
__global__ __launch_bounds__(256, 2) void k_score(const float* __restrict__ cov16,
                                                  const float* __restrict__ cw,
                                                  const float* __restrict__ pre,
                                                  const float* __restrict__ mask,
                                                  const float* __restrict__ dz,
                                                  const float* __restrict__ wattT,
                                                  const float* __restrict__ gv,
                                                  const float* __restrict__ gb,
                                                  const float* __restrict__ enc,
                                                  const float* __restrict__ att_prev,
                                                  float* __restrict__ out_prev,
                                                  float* __restrict__ vbuf,
                                                  float* __restrict__ pm,
                                                  float* __restrict__ ps,
                                                  float* __restrict__ pcb) {
    __shared__ float cov_s[HB + 2 * PAD];   // 232
    __shared__ float mask_s[HB];
    __shared__ float pc[8][NCH][HB];        // partial conv per tap-eighth (10 KB)
    __shared__ float cfT[HB * 12];          // conv result, [h][c] padded to 12
    __shared__ float ew[4][HB];             // per-wave e partials
    __shared__ float wt[HB];                // exp(v - M_b)

    int tid = threadIdx.x, b = blockIdx.x;
    int h0 = b * HB;
    int lane = tid & 63, wv = tid >> 6;

    // stage LDS: cov window (sum the 16 n-partials) + mask
    for (int i = tid; i < HB + 2 * PAD; i += 256) {
        int g = h0 - PAD + i;
        float s = 0.f;
        if (g >= 0 && g < H_LEN) {
            #pragma unroll
            for (int q = 0; q < NCOVP; ++q) s += cov16[q * H_LEN + g];
        }
        cov_s[i] = s;
    }
    if (tid < HB) mask_s[tid] = mask[h0 + tid];

    // per-thread weights, ALL coalesced float2 (a = 128*wv + 2*lane)
    int a = (wv << 7) + (lane << 1);
    float2 dz2 = *(const float2*)(dz + a);
    float2 gv2 = *(const float2*)(gv + a);
    float W0[NCH], W1[NCH];
    #pragma unroll
    for (int c = 0; c < NCH; ++c) {
        float2 w = *(const float2*)(wattT + c * ATT_DIM + a);
        W0[c] = w.x; W1[c] = w.y;
    }
    float bias = gb[0];
    __syncthreads();

    // conv: 8 tap-groups (q = tid>>5, ~25 taps each), h = tid&31
    {
        int h = tid & 31, q = tid >> 5;            // q in [0,8)
        int k0 = (q * KFILT) / 8, k1 = ((q + 1) * KFILT) / 8;
        float acc[NCH];
        #pragma unroll
        for (int c = 0; c < NCH; ++c) acc[c] = 0.f;
        for (int k = k0; k < k1; ++k) {
            float s = cov_s[h + k];
            #pragma unroll
            for (int c = 0; c < NCH; ++c) acc[c] += s * cw[c * KFILT + k];
        }
        #pragma unroll
        for (int c = 0; c < NCH; ++c) pc[q][c][h] = acc[c];   // distinct slot per q
    }
    __syncthreads();
    for (int i = tid; i < NCH * HB; i += 256) {     // 320 entries
        int c = i >> 5, h = i & 31;
        float s = 0.f;
        #pragma unroll
        for (int q = 0; q < 8; ++q) s += pc[q][c][h];
        cfT[h * 12 + c] = s;
    }
    __syncthreads();

    // score: every thread computes its 2-a contribution for ALL 32 h.
    // pre reads: coalesced float2; cf reads: 3 broadcast ds_read_b128 per h.
    float ea[HB];
    const float2* pre2 = (const float2*)pre;
    int colf2 = (wv << 6) + lane;                   // float2 column = a/2
    #pragma unroll
    for (int hc = 0; hc < HB; hc += 8) {
        float2 Pr[8];
        #pragma unroll
        for (int j = 0; j < 8; ++j) Pr[j] = pre2[(h0 + hc + j) * 256 + colf2];
        #pragma unroll
        for (int j = 0; j < 8; ++j) {
            int h = hc + j;
            const float4* cp = (const float4*)&cfT[h * 12];
            float4 c0 = cp[0], c1 = cp[1], c2 = cp[2];
            float ch[NCH] = {c0.x, c0.y, c0.z, c0.w, c1.x, c1.y, c1.z, c1.w, c2.x, c2.y};
            float x0 = Pr[j].x + dz2.x;
            float x1 = Pr[j].y + dz2.y;
            #pragma unroll
            for (int c = 0; c < NCH; ++c) { x0 += ch[c] * W0[c]; x1 += ch[c] * W1[c]; }
            x0 = fminf(fmaxf(x0, -15.f), 15.f);
            x1 = fminf(fmaxf(x1, -15.f), 15.f);
            float z0 = __expf(2.f * x0), z1 = __expf(2.f * x1);
            float t0 = (z0 - 1.f) * __builtin_amdgcn_rcpf(z0 + 1.f);
            float t1 = (z1 - 1.f) * __builtin_amdgcn_rcpf(z1 + 1.f);
            ea[h] = t0 * gv2.x + t1 * gv2.y;
        }
    }

    // reduce-scatter butterfly, single shuffle per fold (31 + 1 shuffles).
    // After 5 halving steps lane holds h = lane>>1; off=1 completes the sum.
    #pragma unroll
    for (int k = 0; k < 16; ++k) {
        float lo = ea[k], hi = ea[k + 16];
        float send = (lane & 32) ? lo : hi;
        float recv = __shfl_xor(send, 32, 64);
        ea[k] = ((lane & 32) ? hi : lo) + recv;
    }
    #pragma unroll
    for (int k = 0; k < 8; ++k) {
        float lo = ea[k], hi = ea[k + 8];
        float send = (lane & 16) ? lo : hi;
        float recv = __shfl_xor(send, 16, 64);
        ea[k] = ((lane & 16) ? hi : lo) + recv;
    }
    #pragma unroll
    for (int k = 0; k < 4; ++k) {
        float lo = ea[k], hi = ea[k + 4];
        float send = (lane & 8) ? lo : hi;
        float recv = __shfl_xor(send, 8, 64);
        ea[k] = ((lane & 8) ? hi : lo) + recv;
    }
    #pragma unroll
    for (int k = 0; k < 2; ++k) {
        float lo = ea[k], hi = ea[k + 2];
        float send = (lane & 4) ? lo : hi;
        float recv = __shfl_xor(send, 4, 64);
        ea[k] = ((lane & 4) ? hi : lo) + recv;
    }
    {
        float lo = ea[0], hi = ea[1];
        float send = (lane & 2) ? lo : hi;
        float recv = __shfl_xor(send, 2, 64);
        ea[0] = ((lane & 2) ? hi : lo) + recv;
    }
    ea[0] += __shfl_xor(ea[0], 1, 64);
    if ((lane & 1) == 0) ew[wv][lane >> 1] = ea[0];
    __syncthreads();

    // wave 0: combine 4 wave-partials, scale, block softmax partials
    if (wv == 0) {
        float v = -1e30f;
        if (lane < HB) {
            float e = ew[0][lane] + ew[1][lane] + ew[2][lane] + ew[3][lane];
            v = 2.f * (e + bias + mask_s[lane]);
            vbuf[h0 + lane] = v;
        }
        float m = v;
        #pragma unroll
        for (int off = 32; off > 0; off >>= 1) m = fmaxf(m, __shfl_xor(m, off, 64));
        float ev = (lane < HB) ? __expf(v - m) : 0.f;
        if (lane < HB) wt[lane] = ev;
        float s = ev;
        #pragma unroll
        for (int off = 32; off > 0; off >>= 1) s += __shfl_xor(s, off, 64);
        if (lane == 0) { pm[b] = m; ps[b] = s; }
    }
    __syncthreads();

    // unnormalized context partial: thread t owns enc cols {2t, 2t+1}
    const float2* enc2 = (const float2*)enc;
    float2 acc0 = {0.f, 0.f}, acc1 = {0.f, 0.f};
    #pragma unroll
    for (int h = 0; h < HB; h += 2) {
        float w0 = wt[h], w1 = wt[h + 1];
        float2 e0 = enc2[(h0 + h) * 256 + tid];
        float2 e1 = enc2[(h0 + h + 1) * 256 + tid];
        acc0.x += w0 * e0.x; acc0.y += w0 * e0.y;
        acc1.x += w1 * e1.x; acc1.y += w1 * e1.y;
    }
    float2 accv = {acc0.x + acc1.x, acc0.y + acc1.y};
    ((float2*)pcb)[b * 256 + tid] = accv;

    // att_prev copy slice (tail, no barrier): block b copies float4 range
    // [b*1024, b*1024+1024). Reads are L3-hot (k_prep just read them).
    {
        const float4* ap4 = (const float4*)att_prev;
        float4* op4 = (float4*)out_prev;
        int ci = b * 1024 + tid;
        #pragma unroll
        for (int r = 0; r < 4; ++r) op4[ci + 256 * r] = ap4[ci + 256 * r];
    }
}

// ---------------------------------------------------------------------------
// K3: finalize. 256 blocks x 256 thr. Redundant merge of 512 (m,s) partials
// (2 KB, L2-hot); block b writes w for 64 h; reduces pcb rows {2b,2b+1} into
// out_c with rescale, via atomics (256 adds/address).  (verified form)
__global__ __launch_bounds__(256) void k_final(const float* __restrict__ vbuf,
                                               const float* __restrict__ pm,
                                               const float* __restrict__ ps,
                                               const float* __restrict__ pcb,
                                               float* __restrict__ out_w,
                                               float* __restrict__ out_c) {
    __shared__ float redA[4], redB[4];
    int tid = threadIdx.x, b = blockIdx.x;
    int lane = tid & 63, wv = tid >> 6;

    float m0 = pm[tid], m1 = pm[tid + 256];
    float s0 = ps[tid], s1 = ps[tid + 256];
    float m = fmaxf(m0, m1);
    #pragma unroll
    for (int off = 32; off > 0; off >>= 1) m = fmaxf(m, __shfl_xor(m, off, 64));
    if (lane == 0) redA[wv] = m;
    __syncthreads();
    float M = fmaxf(fmaxf(redA[0], redA[1]), fmaxf(redA[2], redA[3]));
    float s = s0 * __expf(m0 - M) + s1 * __expf(m1 - M);
    #pragma unroll
    for (int off = 32; off > 0; off >>= 1) s += __shfl_xor(s, off, 64);
    if (lane == 0) redB[wv] = s;
    __syncthreads();
    float S = redB[0] + redB[1] + redB[2] + redB[3];
    float rinv = 1.f / S;

    // w output: 64 h per block
    if (tid < 64) {
        int h = b * 64 + tid;
        out_w[h] = __expf(vbuf[h] - M) * rinv;
    }

    // context reduction: rows 2b, 2b+1 of pcb
    int r0 = 2 * b, r1 = 2 * b + 1;
    float sc0 = __expf(pm[r0] - M) * rinv;
    float sc1 = __expf(pm[r1] - M) * rinv;
    float v0 = pcb[r0 * EPROJS + tid] * sc0 + pcb[r1 * EPROJS + tid] * sc1;
    float v1 = pcb[r0 * EPROJS + tid + 256] * sc0 + pcb[r1 * EPROJS + tid + 256] * sc1;
    atomicAdd(&out_c[tid], v0);
    atomicAdd(&out_c[tid + 256], v1);
}

// ---------------------------------------------------------------------------
extern "C" void kernel_launch(void* const* d_in, const int* in_sizes, int n_in,
                              void* d_out, int out_size, void* d_ws, size_t ws_size,
                              hipStream_t stream) {
    const float* dec_z      = (const float*)d_in[0];
    const float* att_prev   = (const float*)d_in[1];
    const float* pre        = (const float*)d_in[2];
    const float* enc_h      = (const float*)d_in[3];
    const float* mask       = (const float*)d_in[4];
    const float* loc_conv_w = (const float*)d_in[5];
    const float* mlp_att_w  = (const float*)d_in[6];
    const float* mlp_dec_w  = (const float*)d_in[7];
    const float* gvec_w     = (const float*)d_in[8];
    const float* gvec_b     = (const float*)d_in[9];

    float* out_c    = (float*)d_out;                  // [512]
    float* out_prev = out_c + EPROJS;                 // [128*16384]
    float* out_w    = out_prev + N_PREV * H_LEN;      // [16384]

    float* ws    = (float*)d_ws;
    float* cov16 = ws;                                // 16*16384
    float* dz    = cov16 + NCOVP * H_LEN;             // 512
    float* vb    = dz + ATT_DIM;                      // 16384
    float* pm    = vb + H_LEN;                        // 512
    float* ps    = pm + NB_SCORE;                     // 512
    float* pcb   = ps + NB_SCORE;                     // 512*512
    float* wattT = pcb + NB_SCORE * EPROJS;           // 10*512

    k_prep<<<385, 256, 0, stream>>>(att_prev, mlp_dec_w, dec_z, mlp_att_w,
                                    cov16, dz, wattT, out_c);
    k_score<<<NB_SCORE, 256, 0, stream>>>(cov16, loc_conv_w, pre, mask, dz, wattT,
                                          gvec_w, gvec_b, enc_h, att_prev, out_prev,
                                          vb, pm, ps, pcb);
    k_final<<<NB_FIN, 256, 0, stream>>>(vb, pm, ps, pcb, out_w, out_c);
}